// Round 5
// baseline (126.127 us; speedup 1.0000x reference)
//
#include <hip/hip_runtime.h>
#include <hip/hip_bf16.h>

typedef __attribute__((ext_vector_type(4))) float f32x4;
typedef __attribute__((ext_vector_type(16))) float f32x16;
typedef __attribute__((ext_vector_type(8))) short s16x8;
typedef unsigned int u32;

#define DEVINL static __device__ __forceinline__

constexpr int TDIM = 4096;
constexpr int DDIM = 128;
// softmax logit scale folded into Q projection: log2(e) / sqrt(T)
constexpr float QSCALE = 1.4426950408889634f / 64.0f;

DEVINL unsigned short f2bf(float f) {
  union { float f; unsigned u; } v; v.f = f;
  unsigned r = v.u + 0x7fffu + ((v.u >> 16) & 1u);
  return (unsigned short)(r >> 16);
}

// ---------------- kernel 0: W -> W^T (bf16) ----------------
__global__ void wtrans_kernel(const float* __restrict__ Wq,
                              const float* __restrict__ Wk,
                              unsigned short* __restrict__ Wtq,
                              unsigned short* __restrict__ Wtk) {
  const float* src = blockIdx.x ? Wk : Wq;
  unsigned short* dst = blockIdx.x ? Wtk : Wtq;
  int tid = threadIdx.x;
  for (int k = 0; k < 64; ++k) {
    int e = tid + k * 256;
    int h = e >> 7, d = e & 127;
    dst[h * 128 + d] = f2bf(src[d * 128 + h]);
  }
}

// ---------------- kernel 1: Q/K projection + V^T ----------------
// Layouts:
//   Qb[t][.]: byte = t*256 + ((h*2) ^ ((t&15)<<4))   (row-swizzled, LDS-free read)
//   Kb: per 64-kv tile (16 KB), REGISTER-ORDER chunks for direct global->VGPR:
//       byte = (r>>5)*8192 + d4*1024 + (((h>>3)&1)*32 + (r&31))*16 + (h&7)*2
//       -> attn's K-load d4 is one contiguous, coalesced 1 KB per wave.
//   Vt tile: byte = dp*256 + ((half*128 + tl*2) ^ ((dp&15)<<4)), dp=d>>1, half=d&1
__global__ __launch_bounds__(256) void proj_kernel(
    const float* __restrict__ H, const float* __restrict__ bq,
    const float* __restrict__ bk, const unsigned short* __restrict__ Wtq,
    const unsigned short* __restrict__ Wtk, char* __restrict__ Qb,
    char* __restrict__ Kb, char* __restrict__ Vt) {
  __shared__ __align__(16) unsigned short hs[64][136];
  __shared__ __align__(16) char qs[16384];
  __shared__ __align__(16) char kt[16384];
  __shared__ __align__(16) char vt[16384];
  int b = blockIdx.x;
  int n = b >> 6;
  int t0 = (b & 63) << 6;
  int tid = threadIdx.x;
  const float* Hrow = H + (size_t)(n * TDIM + t0) * DDIM;
#pragma unroll
  for (int k = 0; k < 8; ++k) {
    int e = tid + k * 256;
    int r = e >> 5;            // t-local 0..63
    int c = (e & 31) << 2;     // d 0..124
    f32x4 v = *(const f32x4*)(Hrow + r * DDIM + c);
    unsigned short bf[4] = {f2bf(v.x), f2bf(v.y), f2bf(v.z), f2bf(v.w)};
    unsigned short* p = &hs[r][c];
    p[0] = bf[0]; p[1] = bf[1]; p[2] = bf[2]; p[3] = bf[3];
    // build V^T tile (paired 256B rows, swizzle baked)
#pragma unroll
    for (int j = 0; j < 4; ++j) {
      int d = c + j;
      int byte = ((d >> 1) * 256 + (d & 1) * 128 + r * 2) ^
                 (((d >> 1) & 15) << 4);
      *(unsigned short*)(vt + byte) = bf[j];
    }
  }
  __syncthreads();
  int w = tid >> 6, ln = tid & 63;
  int lm = ln & 15, lg = ln >> 4;
  int m0 = w * 16;
  s16x8 af[4];
#pragma unroll
  for (int kf = 0; kf < 4; ++kf)
    af[kf] = *(const s16x8*)&hs[m0 + lm][kf * 32 + lg * 8];
  // Q projection -> qs (QSCALE folded)
#pragma unroll
  for (int nt = 0; nt < 8; ++nt) {
    f32x4 acc = {0.f, 0.f, 0.f, 0.f};
#pragma unroll
    for (int kf = 0; kf < 4; ++kf) {
      s16x8 bfr = *(const s16x8*)&Wtq[(nt * 16 + lm) * 128 + kf * 32 + lg * 8];
      acc = __builtin_amdgcn_mfma_f32_16x16x32_bf16(af[kf], bfr, acc, 0, 0, 0);
    }
    int h = nt * 16 + lm;
    float bv = bq[h];
#pragma unroll
    for (int i = 0; i < 4; ++i) {
      int tl = m0 + lg * 4 + i;
      int byte = tl * 256 + ((h * 2) ^ ((tl & 15) << 4));
      *(unsigned short*)(qs + byte) = f2bf((acc[i] + bv) * QSCALE);
    }
  }
  // K projection -> kt (register-order chunk layout)
#pragma unroll
  for (int nt = 0; nt < 8; ++nt) {
    f32x4 acc = {0.f, 0.f, 0.f, 0.f};
#pragma unroll
    for (int kf = 0; kf < 4; ++kf) {
      s16x8 bfr = *(const s16x8*)&Wtk[(nt * 16 + lm) * 128 + kf * 32 + lg * 8];
      acc = __builtin_amdgcn_mfma_f32_16x16x32_bf16(af[kf], bfr, acc, 0, 0, 0);
    }
    int hip2 = ((lm >> 3) & 1) * 32;  // hi' slot
    int jj = lm & 7;
#pragma unroll
    for (int i = 0; i < 4; ++i) {
      int rl = m0 + lg * 4 + i;
      int byte = (rl >> 5) * 8192 + nt * 1024 + (hip2 + (rl & 31)) * 16 + jj * 2;
      *(unsigned short*)(kt + byte) = f2bf(acc[i] + bk[nt * 16 + lm]);
    }
  }
  __syncthreads();
  // coalesced flush: 16KB each, b128
  size_t base = (size_t)(n * TDIM + t0) * 256;
  size_t vbase = ((size_t)(n * 64 + (t0 >> 6)) << 14);
#pragma unroll
  for (int k = 0; k < 4; ++k) {
    int off = tid * 16 + k * 4096;
    *(f32x4*)(Qb + base + off) = *(const f32x4*)(qs + off);
    *(f32x4*)(Kb + base + off) = *(const f32x4*)(kt + off);
    *(f32x4*)(Vt + vbase + off) = *(const f32x4*)(vt + off);
  }
}

// async global -> LDS, 16 KiB tile, 8 waves x 2 x 1 KiB
DEVINL void stage16(const char* g, char* s, int w, int ln) {
#pragma unroll
  for (int j = 0; j < 2; ++j) {
    int off = (w * 2 + j) * 1024;
    __builtin_amdgcn_global_load_lds(
        (const __attribute__((address_space(1))) void*)(g + off + ln * 16),
        (__attribute__((address_space(3))) void*)(s + off), 16, 0, 0);
  }
}

// ---------------- kernel 2: flash attention + residual ----------------
// 256 blocks x 512 thr (8 waves). 128 q/block, 32 q/wave via 32x32 MFMA.
// Split-KV: waves 0-3 kv[0,2048), waves 4-7 kv[2048,4096); pure-add merge.
// K: streamed global->VGPR (coalesced 1KB chunks, L1/L2-served) — no LDS.
// V: LDS double-buffered via global_load_lds. No-max softmax; in-register P.
__global__ __launch_bounds__(512, 2) void attn_kernel(
    const char* __restrict__ Qsw, const char* __restrict__ Ksw,
    const char* __restrict__ Vsw, const float* __restrict__ H,
    float* __restrict__ Out) {
  __shared__ __align__(16) char lds[69632];
  int b = blockIdx.x;
  int n = b & 7;  // batch per XCD: K/V L2-resident
  int q0 = (b >> 3) << 7;
  int tid = threadIdx.x;
  int w = tid >> 6, ln = tid & 63;
  int q32 = ln & 31, hi = ln >> 5;
  int ws = w & 3;   // q sub-block
  int st = w >> 2;  // kv stream
  int qrow = q0 + ws * 32;
  int swz = (q32 & 15) << 4;        // Q row swizzle key
  int dpl = q32 >> 1;               // V paired-row index low bits
  int vswz = dpl << 4;
  int dphalf = (q32 & 1) * 128;

  const char* Kn = Ksw + (size_t)n * (TDIM * 256);
  const char* Vn0 = Vsw + (size_t)n * (64 * 16384);
  const char* Vn1 = Vn0 + (size_t)32 * 16384;

  // Q fragments (global rows XOR-swizzled)
  const char* Qn = Qsw + (size_t)(n * TDIM + qrow + q32) * 256;
  s16x8 qf[8];
#pragma unroll
  for (int d = 0; d < 8; ++d)
    qf[d] = *(const s16x8*)(Qn + ((d * 32 + hi * 16) ^ swz));

  f32x16 o[4];
#pragma unroll
  for (int dt = 0; dt < 4; ++dt) o[dt] = (f32x16)0.0f;
  float lsum = 0.f;

  // prologue: stage iter-0 V tiles for both streams
  stage16(Vn0, lds + 0, w, ln);
  stage16(Vn1, lds + 32768, w, ln);
  __syncthreads();

  for (int it = 0; it < 32; ++it) {
    int c = it & 1;
    if (it < 31) {
      int p2 = c ^ 1;
      size_t go = (size_t)(it + 1) * 16384;
      stage16(Vn0 + go, lds + p2 * 16384, w, ln);
      stage16(Vn1 + go, lds + 32768 + p2 * 16384, w, ln);
    }
    const char* vb = lds + st * 32768 + c * 16384;
    const char* kt = Kn + ((size_t)(st * 32 + it) << 14);

    // QK^T swapped: S[k][q], A = K rows (direct from global), B = Q.
    f32x16 s0 = (f32x16)0.0f, s1 = (f32x16)0.0f;
#pragma unroll
    for (int d = 0; d < 8; ++d) {
      s16x8 ka0 = *(const s16x8*)(kt + d * 1024 + ln * 16);
      s16x8 ka1 = *(const s16x8*)(kt + 8192 + d * 1024 + ln * 16);
      s0 = __builtin_amdgcn_mfma_f32_32x32x16_bf16(ka0, qf[d], s0, 0, 0, 0);
      s1 = __builtin_amdgcn_mfma_f32_32x32x16_bf16(ka1, qf[d], s1, 0, 0, 0);
    }

    // softmax numerator: plain exp2 (no max: |logit| bounded tiny)
    f32x16 p0, p1;
#pragma unroll
    for (int r = 0; r < 16; ++r) {
      p0[r] = __builtin_amdgcn_exp2f(s0[r]);
      p1[r] = __builtin_amdgcn_exp2f(s1[r]);
    }
    float ls = 0.f;
#pragma unroll
    for (int r = 0; r < 16; ++r) ls += p0[r] + p1[r];
    lsum += ls;

    // P -> PV A-fragments fully in-register (T12)
    s16x8 pa[4];
#pragma unroll
    for (int kt2 = 0; kt2 < 2; ++kt2) {
      u32 P2[8];
#pragma unroll
      for (int r = 0; r < 8; ++r) {
        float e0 = kt2 ? p1[2 * r] : p0[2 * r];
        float e1 = kt2 ? p1[2 * r + 1] : p0[2 * r + 1];
        asm("v_cvt_pk_bf16_f32 %0, %1, %2" : "=v"(P2[r]) : "v"(e0), "v"(e1));
      }
#pragma unroll
      for (int b2 = 0; b2 < 2; ++b2) {
        u32 a0 = P2[b2 * 4 + 0], c0 = P2[b2 * 4 + 2];
        u32 a1 = P2[b2 * 4 + 1], c1 = P2[b2 * 4 + 3];
        asm("v_permlane32_swap_b32 %0, %1" : "+v"(a0), "+v"(c0));
        asm("v_permlane32_swap_b32 %0, %1" : "+v"(a1), "+v"(c1));
        union { u32 u[4]; s16x8 v; } pk;
        pk.u[0] = a0; pk.u[1] = a1; pk.u[2] = c0; pk.u[3] = c1;
        pa[kt2 * 2 + b2] = pk.v;
      }
    }

    // PV: o[dt] += P * V, B-frag from paired-row V^T LDS
    __builtin_amdgcn_s_setprio(1);
#pragma unroll
    for (int ks = 0; ks < 4; ++ks) {
      int colv = dphalf + ks * 32 + hi * 16;
#pragma unroll
      for (int dt = 0; dt < 4; ++dt) {
        int dp = dt * 16 + dpl;
        s16x8 vv = *(const s16x8*)(vb + ((dp * 256 + colv) ^ vswz));
        o[dt] = __builtin_amdgcn_mfma_f32_32x32x16_bf16(pa[ks], vv, o[dt], 0, 0, 0);
      }
    }
    __builtin_amdgcn_s_setprio(0);
    __syncthreads();  // V buffer handoff (drains V stage vmcnt)
  }

  // ---- split-KV merge: waves 4-7 dump o,l; waves 0-3 add ----
  if (w >= 4) {
    char* dst = lds + (w - 4) * 16896;
#pragma unroll
    for (int dt = 0; dt < 4; ++dt)
#pragma unroll
      for (int c4 = 0; c4 < 4; ++c4) {
        f32x4 ch = {o[dt][c4 * 4 + 0], o[dt][c4 * 4 + 1],
                    o[dt][c4 * 4 + 2], o[dt][c4 * 4 + 3]};
        *(f32x4*)(dst + ((dt * 4 + c4) * 64 + ln) * 16) = ch;
      }
    *(float*)(dst + 16384 + ln * 4) = lsum;
  }
  __syncthreads();
  if (w < 4) {
    const char* src = lds + w * 16896;
#pragma unroll
    for (int dt = 0; dt < 4; ++dt)
#pragma unroll
      for (int c4 = 0; c4 < 4; ++c4) {
        f32x4 ch = *(const f32x4*)(src + ((dt * 4 + c4) * 64 + ln) * 16);
        o[dt][c4 * 4 + 0] += ch.x; o[dt][c4 * 4 + 1] += ch.y;
        o[dt][c4 * 4 + 2] += ch.z; o[dt][c4 * 4 + 3] += ch.w;
      }
    lsum += *(const float*)(src + 16384 + ln * 4);
    // cross-half l: lanes l and l+32 hold disjoint k-partials for q=q32
    u32 la = __builtin_bit_cast(u32, lsum), lb = la;
    asm("v_permlane32_swap_b32 %0, %1" : "+v"(la), "+v"(lb));
    float ltot = __builtin_bit_cast(float, la) + __builtin_bit_cast(float, lb);
    float invl = 1.0f / ltot;
    if (hi == 0) *(float*)(lds + 67584 + w * 128 + q32 * 4) = invl;
  }
  __syncthreads();
  if (w < 4) {
    const float* Hn = H + (size_t)n * TDIM * DDIM;
    float* On = Out + (size_t)n * TDIM * DDIM;
    float iv[16];
#pragma unroll
    for (int r = 0; r < 16; ++r) {
      int qr = (r & 3) + 8 * (r >> 2) + 4 * hi;
      iv[r] = *(const float*)(lds + 67584 + w * 128 + qr * 4);
    }
#pragma unroll
    for (int dt = 0; dt < 4; ++dt)
#pragma unroll
      for (int r = 0; r < 16; ++r) {
        int qr = (r & 3) + 8 * (r >> 2) + 4 * hi;
        size_t idx = (size_t)(qrow + qr) * DDIM + dt * 32 + q32;
        On[idx] = o[dt][r] * iv[r] + Hn[idx];
      }
  }
}

extern "C" void kernel_launch(void* const* d_in, const int* in_sizes, int n_in,
                              void* d_out, int out_size, void* d_ws, size_t ws_size,
                              hipStream_t stream) {
  const float* H  = (const float*)d_in[0];
  const float* Wq = (const float*)d_in[1];
  const float* bq = (const float*)d_in[2];
  const float* Wk = (const float*)d_in[3];
  const float* bk = (const float*)d_in[4];
  float* Out = (float*)d_out;
  char* ws = (char*)d_ws;
  unsigned short* Wtq = (unsigned short*)(ws);
  unsigned short* Wtk = (unsigned short*)(ws + 32768);
  char* Qb = ws + 65536;
  char* Kb = ws + 65536 + 8388608;
  char* Vt = ws + 65536 + 2 * 8388608;

  wtrans_kernel<<<2, 256, 0, stream>>>(Wq, Wk, Wtq, Wtk);
  proj_kernel<<<512, 256, 0, stream>>>(H, bq, bk, Wtq, Wtk, Qb, Kb, Vt);
  attn_kernel<<<256, 512, 0, stream>>>(Qb, Kb, Vt, H, Out);
}

// Round 6
// 117.161 us; speedup vs baseline: 1.0765x; 1.0765x over previous
//
#include <hip/hip_runtime.h>
#include <hip/hip_bf16.h>

typedef __attribute__((ext_vector_type(4))) float f32x4;
typedef __attribute__((ext_vector_type(16))) float f32x16;
typedef __attribute__((ext_vector_type(8))) short s16x8;
typedef unsigned int u32;

#define DEVINL static __device__ __forceinline__

constexpr int TDIM = 4096;
constexpr int DDIM = 128;
// softmax logit scale folded into Q' projection: log2(e) / sqrt(T)
constexpr float QSCALE = 1.4426950408889634f / 64.0f;

DEVINL unsigned short f2bf(float f) {
  union { float f; unsigned u; } v; v.f = f;
  unsigned r = v.u + 0x7fffu + ((v.u >> 16) & 1u);
  return (unsigned short)(r >> 16);
}

// ---------------- kernel 0: M = Wq Wk^T (bf16, B-frag layout), u = Wk bq ----
// S[t,s] = (h_t M + u)·h_s + rowconst(t) + const; rowconst cancels in softmax.
__global__ __launch_bounds__(256) void prep_kernel(
    const float* __restrict__ Wq, const float* __restrict__ Wk,
    const float* __restrict__ bq, unsigned short* __restrict__ Mt,
    float* __restrict__ u) {
  int idx = blockIdx.x * 256 + threadIdx.x;  // 16384 entries
  int e = idx >> 7, d = idx & 127;
  float acc = 0.f;
#pragma unroll 4
  for (int h = 0; h < 128; ++h) acc += Wq[d * 128 + h] * Wk[e * 128 + h];
  Mt[e * 128 + d] = f2bf(acc);  // Mt[e][d] = M[d][e]
  if (blockIdx.x == 0 && threadIdx.x < 128) {
    float a = 0.f;
#pragma unroll 4
    for (int h = 0; h < 128; ++h) a += Wk[threadIdx.x * 128 + h] * bq[h];
    u[threadIdx.x] = a;
  }
}

// ---------------- kernel 1: Q' projection + H transcodes ----------------
// Layouts (swizzle baked into global, G21 both-sides):
//   Qb[t][.]: byte = t*256 + ((e*2) ^ ((t&15)<<4))
//   Kb[r][.]: byte = r*256 + ((d*2) ^ ((r&15)<<4))            (bf16 H rows)
//   Vt: per 32-kv tile (8 KB): byte = dp*128 + ((half*64 + tl*2) ^ ((dp&7)<<4)),
//       dp = d>>1, half = d&1, tl = kv&31  (bf16 H^T paired rows)
__global__ __launch_bounds__(256) void proj_kernel(
    const float* __restrict__ H, const unsigned short* __restrict__ Mt,
    const float* __restrict__ u, char* __restrict__ Qb,
    char* __restrict__ Kb, char* __restrict__ Vt) {
  __shared__ __align__(16) unsigned short hs[64][136];
  __shared__ __align__(16) char qs[16384];
  __shared__ __align__(16) char kt[16384];
  __shared__ __align__(16) char vt[16384];
  int b = blockIdx.x;
  int n = b >> 6;
  int t0 = (b & 63) << 6;
  int tid = threadIdx.x;
  const float* Hrow = H + (size_t)(n * TDIM + t0) * DDIM;
#pragma unroll
  for (int k = 0; k < 8; ++k) {
    int e = tid + k * 256;
    int r = e >> 5;            // t-local 0..63
    int c = (e & 31) << 2;     // d 0..124
    f32x4 v = *(const f32x4*)(Hrow + r * DDIM + c);
    unsigned short bf[4] = {f2bf(v.x), f2bf(v.y), f2bf(v.z), f2bf(v.w)};
    unsigned short* p = &hs[r][c];
    p[0] = bf[0]; p[1] = bf[1]; p[2] = bf[2]; p[3] = bf[3];
    // Kb tile: 8B block survives the 16B-granule XOR intact
    int kbyte = r * 256 + ((c * 2) ^ ((r & 15) << 4));
    unsigned short* kp = (unsigned short*)(kt + kbyte);
    kp[0] = bf[0]; kp[1] = bf[1]; kp[2] = bf[2]; kp[3] = bf[3];
    // Vt paired-row tiles (2 per block: tl>>5)
    int p32 = r >> 5, tl = r & 31;
#pragma unroll
    for (int j = 0; j < 4; ++j) {
      int d = c + j;
      int dp = d >> 1, half = d & 1;
      int byte = p32 * 8192 + dp * 128 +
                 ((half * 64 + tl * 2) ^ ((dp & 7) << 4));
      *(unsigned short*)(vt + byte) = bf[j];
    }
  }
  __syncthreads();
  int w = tid >> 6, ln = tid & 63;
  int lm = ln & 15, lg = ln >> 4;
  int m0 = w * 16;
  s16x8 af[4];
#pragma unroll
  for (int kf = 0; kf < 4; ++kf)
    af[kf] = *(const s16x8*)&hs[m0 + lm][kf * 32 + lg * 8];
  // Q' = H M + u, scaled by QSCALE
#pragma unroll
  for (int nt = 0; nt < 8; ++nt) {
    f32x4 acc = {0.f, 0.f, 0.f, 0.f};
#pragma unroll
    for (int kf = 0; kf < 4; ++kf) {
      s16x8 bfr = *(const s16x8*)&Mt[(nt * 16 + lm) * 128 + kf * 32 + lg * 8];
      acc = __builtin_amdgcn_mfma_f32_16x16x32_bf16(af[kf], bfr, acc, 0, 0, 0);
    }
    int e = nt * 16 + lm;
    float bv = u[e];
#pragma unroll
    for (int i = 0; i < 4; ++i) {
      int tl = m0 + lg * 4 + i;
      int byte = tl * 256 + ((e * 2) ^ ((tl & 15) << 4));
      *(unsigned short*)(qs + byte) = f2bf((acc[i] + bv) * QSCALE);
    }
  }
  __syncthreads();
  // coalesced flush: 16KB each, b128
  size_t base = (size_t)(n * TDIM + t0) * 256;
  size_t vbase = (size_t)(n * 128 + (t0 >> 5)) * 8192;
#pragma unroll
  for (int k = 0; k < 4; ++k) {
    int off = tid * 16 + k * 4096;
    *(f32x4*)(Qb + base + off) = *(const f32x4*)(qs + off);
    *(f32x4*)(Kb + base + off) = *(const f32x4*)(kt + off);
    *(f32x4*)(Vt + vbase + off) = *(const f32x4*)(vt + off);
  }
}

// async global -> LDS, 8 KiB per wave
DEVINL void stage8(const char* g, char* s, int ln) {
#pragma unroll
  for (int j = 0; j < 8; ++j) {
    __builtin_amdgcn_global_load_lds(
        (const __attribute__((address_space(1))) void*)(g + j * 1024 + ln * 16),
        (__attribute__((address_space(3))) void*)(s + j * 1024), 16, 0, 0);
  }
}

// ---------------- kernel 2: flash attention + residual ----------------
// 256 blocks x 512 thr = 2 q-groups (64 q/wave!) x 4 kv-streams. KVBLK=32.
// K = raw H (M-trick). Each K/V LDS fragment feeds TWO MFMAs (q-lo/q-hi):
// operand reads halve vs 32q/wave. No-max softmax; in-register P (T12).
__global__ __launch_bounds__(512, 2) void attn_kernel(
    const char* __restrict__ Qsw, const char* __restrict__ Ksw,
    const char* __restrict__ Vsw, const float* __restrict__ H,
    float* __restrict__ Out) {
  __shared__ __align__(16) char lds[131072];
  int b = blockIdx.x;
  int n = b & 7;  // batch per XCD: H tiles L2-resident
  int q0 = (b >> 3) << 7;
  int tid = threadIdx.x;
  int w = tid >> 6, ln = tid & 63;
  int q32 = ln & 31, hi = ln >> 5;
  int qg = w >> 2;   // q-group (64 q)
  int kvs = w & 3;   // kv stream: [kvs*1024, kvs*1024+1024)
  int qrow = q0 + qg * 64;
  int swz = (q32 & 15) << 4;
  int dpl = q32 >> 1;
  int vcol = (q32 & 1) * 64;

  const char* Kn = Ksw + (size_t)n * (TDIM * 256);
  const char* Vn = Vsw + (size_t)n * (128 * 8192);

  // Q' fragments for both 32-col halves
  const char* Qlo = Qsw + (size_t)(n * TDIM + qrow + q32) * 256;
  const char* Qhi = Qlo + 32 * 256;
  s16x8 qfl[8], qfh[8];
#pragma unroll
  for (int d = 0; d < 8; ++d) {
    int off = (d * 32 + hi * 16) ^ swz;
    qfl[d] = *(const s16x8*)(Qlo + off);
    qfh[d] = *(const s16x8*)(Qhi + off);
  }

  f32x16 o[8];
#pragma unroll
  for (int i = 0; i < 8; ++i) o[i] = (f32x16)0.0f;
  float lsl = 0.f, lsh = 0.f;

  // staging role (independent of compute role): wave stages one 8KB tile
  int stp = w & 3, typ = w >> 2;  // typ 0: K-tile, 1: V-tile
  {
    const char* g = typ ? (Vn + (size_t)(stp * 32) * 8192)
                        : (Kn + (size_t)(stp * 1024) * 256);
    stage8(g, lds + stp * 16384 + typ * 8192, ln);
  }
  __syncthreads();

  for (int it = 0; it < 32; ++it) {
    int c = it & 1;
    if (it < 31) {
      int kvn = stp * 1024 + (it + 1) * 32;
      const char* g = typ ? (Vn + (size_t)(kvn >> 5) * 8192)
                          : (Kn + (size_t)kvn * 256);
      stage8(g, lds + (c ^ 1) * 65536 + stp * 16384 + typ * 8192, ln);
    }
    const char* kb = lds + c * 65536 + kvs * 16384;
    const char* vb = kb + 8192;

    // QK^T swapped: S[kv][q]; A = H rows (32 kv), B = Q' halves
    f32x16 sl = (f32x16)0.0f, sh = (f32x16)0.0f;
    __builtin_amdgcn_s_setprio(1);
#pragma unroll
    for (int d = 0; d < 8; ++d) {
      s16x8 ka = *(const s16x8*)(kb + (q32 * 256 + ((d * 32 + hi * 16) ^ swz)));
      sl = __builtin_amdgcn_mfma_f32_32x32x16_bf16(ka, qfl[d], sl, 0, 0, 0);
      sh = __builtin_amdgcn_mfma_f32_32x32x16_bf16(ka, qfh[d], sh, 0, 0, 0);
    }
    __builtin_amdgcn_s_setprio(0);

    // softmax numerator in place (no max: logits tiny) + row sums
#pragma unroll
    for (int r = 0; r < 16; ++r) {
      sl[r] = __builtin_amdgcn_exp2f(sl[r]);
      lsl += sl[r];
      sh[r] = __builtin_amdgcn_exp2f(sh[r]);
      lsh += sh[r];
    }

    // pack P -> A-fragments in-register (T12), per half
    s16x8 pal[2], pah[2];
    {
      u32 P2[8];
#pragma unroll
      for (int r = 0; r < 8; ++r)
        asm("v_cvt_pk_bf16_f32 %0, %1, %2"
            : "=v"(P2[r]) : "v"(sl[2 * r]), "v"(sl[2 * r + 1]));
#pragma unroll
      for (int b2 = 0; b2 < 2; ++b2) {
        u32 a0 = P2[b2 * 4 + 0], c0 = P2[b2 * 4 + 2];
        u32 a1 = P2[b2 * 4 + 1], c1 = P2[b2 * 4 + 3];
        asm("v_permlane32_swap_b32 %0, %1" : "+v"(a0), "+v"(c0));
        asm("v_permlane32_swap_b32 %0, %1" : "+v"(a1), "+v"(c1));
        union { u32 u[4]; s16x8 v; } pk;
        pk.u[0] = a0; pk.u[1] = a1; pk.u[2] = c0; pk.u[3] = c1;
        pal[b2] = pk.v;
      }
#pragma unroll
      for (int r = 0; r < 8; ++r)
        asm("v_cvt_pk_bf16_f32 %0, %1, %2"
            : "=v"(P2[r]) : "v"(sh[2 * r]), "v"(sh[2 * r + 1]));
#pragma unroll
      for (int b2 = 0; b2 < 2; ++b2) {
        u32 a0 = P2[b2 * 4 + 0], c0 = P2[b2 * 4 + 2];
        u32 a1 = P2[b2 * 4 + 1], c1 = P2[b2 * 4 + 3];
        asm("v_permlane32_swap_b32 %0, %1" : "+v"(a0), "+v"(c0));
        asm("v_permlane32_swap_b32 %0, %1" : "+v"(a1), "+v"(c1));
        union { u32 u[4]; s16x8 v; } pk;
        pk.u[0] = a0; pk.u[1] = a1; pk.u[2] = c0; pk.u[3] = c1;
        pah[b2] = pk.v;
      }
    }

    // PV: each V fragment feeds both q-halves
    __builtin_amdgcn_s_setprio(1);
#pragma unroll
    for (int ks = 0; ks < 2; ++ks) {
#pragma unroll
      for (int dt = 0; dt < 4; ++dt) {
        s16x8 vv = *(const s16x8*)(vb + ((dt * 16 + dpl) * 128 +
                        ((vcol + ks * 32 + hi * 16) ^ ((dpl & 7) << 4))));
        o[dt] = __builtin_amdgcn_mfma_f32_32x32x16_bf16(pal[ks], vv, o[dt], 0, 0, 0);
        o[4 + dt] = __builtin_amdgcn_mfma_f32_32x32x16_bf16(pah[ks], vv, o[4 + dt], 0, 0, 0);
      }
    }
    __builtin_amdgcn_s_setprio(0);
    __syncthreads();  // dbuf handoff (drains stage vmcnt)
  }

  // ---- split-KV merge across 4 streams (tree) ----
  // slots: 4 x 32768 alias the tile region; slot(qg,j) = (qg*2+j)*32768
#define DUMP_O(dst)                                                      \
  {                                                                      \
    char* _d = (dst);                                                    \
    _Pragma("unroll") for (int i = 0; i < 8; ++i)                        \
      _Pragma("unroll") for (int c4 = 0; c4 < 4; ++c4) {                 \
        f32x4 ch = {o[i][c4 * 4 + 0], o[i][c4 * 4 + 1],                  \
                    o[i][c4 * 4 + 2], o[i][c4 * 4 + 3]};                 \
        *(f32x4*)(_d + ((i * 4 + c4) * 64 + ln) * 16) = ch;              \
      }                                                                  \
  }
#define ADD_O(src)                                                       \
  {                                                                      \
    const char* _s = (src);                                              \
    _Pragma("unroll") for (int i = 0; i < 8; ++i)                        \
      _Pragma("unroll") for (int c4 = 0; c4 < 4; ++c4) {                 \
        f32x4 ch = *(const f32x4*)(_s + ((i * 4 + c4) * 64 + ln) * 16);  \
        o[i][c4 * 4 + 0] += ch.x; o[i][c4 * 4 + 1] += ch.y;              \
        o[i][c4 * 4 + 2] += ch.z; o[i][c4 * 4 + 3] += ch.w;              \
      }                                                                  \
  }
  if (kvs & 1) DUMP_O(lds + (qg * 2 + (kvs >> 1)) * 32768);
  __syncthreads();
  if (!(kvs & 1)) ADD_O(lds + (qg * 2 + (kvs >> 1)) * 32768);
  __syncthreads();
  if (kvs == 2) DUMP_O(lds + qg * 2 * 32768);
  // all waves dump l-partials into freed slot qg*2+1
  {
    float* lt = (float*)(lds + (qg * 2 + 1) * 32768);
    lt[((kvs * 2 + hi) * 32 + q32) * 2 + 0] = lsl;
    lt[((kvs * 2 + hi) * 32 + q32) * 2 + 1] = lsh;
  }
  __syncthreads();
  if (kvs == 0) {
    ADD_O(lds + qg * 2 * 32768);
    const float* lt = (const float*)(lds + (qg * 2 + 1) * 32768);
    const float* Hn = H + (size_t)n * TDIM * DDIM;
    float* On = Out + (size_t)n * TDIM * DDIM;
#pragma unroll
    for (int r = 0; r < 16; ++r) {
      int qr = (r & 3) + 8 * (r >> 2) + 4 * hi;
      float suml = 0.f, sumh = 0.f;
#pragma unroll
      for (int t8 = 0; t8 < 8; ++t8) {
        suml += lt[(t8 * 32 + qr) * 2 + 0];
        sumh += lt[(t8 * 32 + qr) * 2 + 1];
      }
      float il = 1.0f / suml, ih = 1.0f / sumh;
#pragma unroll
      for (int dt = 0; dt < 4; ++dt) {
        size_t ilo = (size_t)(qrow + qr) * DDIM + dt * 32 + q32;
        size_t ihi = (size_t)(qrow + 32 + qr) * DDIM + dt * 32 + q32;
        On[ilo] = o[dt][r] * il + Hn[ilo];
        On[ihi] = o[4 + dt][r] * ih + Hn[ihi];
      }
    }
  }
#undef DUMP_O
#undef ADD_O
}

extern "C" void kernel_launch(void* const* d_in, const int* in_sizes, int n_in,
                              void* d_out, int out_size, void* d_ws, size_t ws_size,
                              hipStream_t stream) {
  const float* H  = (const float*)d_in[0];
  const float* Wq = (const float*)d_in[1];
  const float* bq = (const float*)d_in[2];
  const float* Wk = (const float*)d_in[3];
  const float* bk = (const float*)d_in[4];
  (void)bk;  // bk contributes only a row-constant logit term (softmax-invariant)
  float* Out = (float*)d_out;
  char* ws = (char*)d_ws;
  unsigned short* Mt = (unsigned short*)(ws);
  float* u = (float*)(ws + 32768);
  char* Qb = ws + 65536;
  char* Kb = ws + 65536 + 8388608;
  char* Vt = ws + 65536 + 2 * 8388608;

  prep_kernel<<<64, 256, 0, stream>>>(Wq, Wk, bq, Mt, u);
  proj_kernel<<<512, 256, 0, stream>>>(H, Mt, u, Qb, Kb, Vt);
  attn_kernel<<<256, 512, 0, stream>>>(Qb, Kb, Vt, H, Out);
}

// Round 7
// 116.155 us; speedup vs baseline: 1.0858x; 1.0087x over previous
//
#include <hip/hip_runtime.h>
#include <hip/hip_bf16.h>

typedef __attribute__((ext_vector_type(4))) float f32x4;
typedef __attribute__((ext_vector_type(16))) float f32x16;
typedef __attribute__((ext_vector_type(8))) short s16x8;
typedef unsigned int u32;

#define DEVINL static __device__ __forceinline__

constexpr int TDIM = 4096;
constexpr int DDIM = 128;
// softmax logit scale folded into Q' projection: log2(e) / sqrt(T)
constexpr float QSCALE = 1.4426950408889634f / 64.0f;

DEVINL unsigned short f2bf(float f) {
  union { float f; unsigned u; } v; v.f = f;
  unsigned r = v.u + 0x7fffu + ((v.u >> 16) & 1u);
  return (unsigned short)(r >> 16);
}

// ---------------- kernel 0: M = Wq Wk^T (bf16, B-frag layout), u = Wk bq ----
// S[t,s] = (h_t M + u)·h_s + rowconst(t) + const; rowconst cancels in softmax.
__global__ __launch_bounds__(256) void prep_kernel(
    const float* __restrict__ Wq, const float* __restrict__ Wk,
    const float* __restrict__ bq, unsigned short* __restrict__ Mt,
    float* __restrict__ u) {
  int idx = blockIdx.x * 256 + threadIdx.x;  // 16384 entries
  int e = idx >> 7, d = idx & 127;
  float acc = 0.f;
#pragma unroll 4
  for (int h = 0; h < 128; ++h) acc += Wq[d * 128 + h] * Wk[e * 128 + h];
  Mt[e * 128 + d] = f2bf(acc);  // Mt[e][d] = M[d][e]
  if (blockIdx.x == 0 && threadIdx.x < 128) {
    float a = 0.f;
#pragma unroll 4
    for (int h = 0; h < 128; ++h) a += Wk[threadIdx.x * 128 + h] * bq[h];
    u[threadIdx.x] = a;
  }
}

// ---------------- kernel 1: Q' projection + H transcodes ----------------
// Layouts (swizzle baked into global, G21 both-sides):
//   Qb[t][.]: byte = t*256 + ((e*2) ^ ((t&15)<<4))
//   Kb[r][.]: byte = r*256 + ((d*2) ^ ((r&15)<<4))            (bf16 H rows)
//   Vt: per 32-kv tile (8 KB): byte = dp*128 + ((half*64 + tl*2) ^ ((dp&7)<<4)),
//       dp = d>>1, half = d&1, tl = kv&31  (bf16 H^T paired rows)
__global__ __launch_bounds__(256) void proj_kernel(
    const float* __restrict__ H, const unsigned short* __restrict__ Mt,
    const float* __restrict__ u, char* __restrict__ Qb,
    char* __restrict__ Kb, char* __restrict__ Vt) {
  __shared__ __align__(16) unsigned short hs[64][136];
  __shared__ __align__(16) char qs[16384];
  __shared__ __align__(16) char kt[16384];
  __shared__ __align__(16) char vt[16384];
  int b = blockIdx.x;
  int n = b >> 6;
  int t0 = (b & 63) << 6;
  int tid = threadIdx.x;
  const float* Hrow = H + (size_t)(n * TDIM + t0) * DDIM;
#pragma unroll
  for (int k = 0; k < 8; ++k) {
    int e = tid + k * 256;
    int r = e >> 5;            // t-local 0..63
    int c = (e & 31) << 2;     // d 0..124
    f32x4 v = *(const f32x4*)(Hrow + r * DDIM + c);
    unsigned short bf[4] = {f2bf(v.x), f2bf(v.y), f2bf(v.z), f2bf(v.w)};
    unsigned short* p = &hs[r][c];
    p[0] = bf[0]; p[1] = bf[1]; p[2] = bf[2]; p[3] = bf[3];
    // Kb tile: 8B block survives the 16B-granule XOR intact
    int kbyte = r * 256 + ((c * 2) ^ ((r & 15) << 4));
    unsigned short* kp = (unsigned short*)(kt + kbyte);
    kp[0] = bf[0]; kp[1] = bf[1]; kp[2] = bf[2]; kp[3] = bf[3];
    // Vt paired-row tiles (2 per block: tl>>5)
    int p32 = r >> 5, tl = r & 31;
#pragma unroll
    for (int j = 0; j < 4; ++j) {
      int d = c + j;
      int dp = d >> 1, half = d & 1;
      int byte = p32 * 8192 + dp * 128 +
                 ((half * 64 + tl * 2) ^ ((dp & 7) << 4));
      *(unsigned short*)(vt + byte) = bf[j];
    }
  }
  __syncthreads();
  int w = tid >> 6, ln = tid & 63;
  int lm = ln & 15, lg = ln >> 4;
  int m0 = w * 16;
  s16x8 af[4];
#pragma unroll
  for (int kf = 0; kf < 4; ++kf)
    af[kf] = *(const s16x8*)&hs[m0 + lm][kf * 32 + lg * 8];
  // Q' = H M + u, scaled by QSCALE
#pragma unroll
  for (int nt = 0; nt < 8; ++nt) {
    f32x4 acc = {0.f, 0.f, 0.f, 0.f};
#pragma unroll
    for (int kf = 0; kf < 4; ++kf) {
      s16x8 bfr = *(const s16x8*)&Mt[(nt * 16 + lm) * 128 + kf * 32 + lg * 8];
      acc = __builtin_amdgcn_mfma_f32_16x16x32_bf16(af[kf], bfr, acc, 0, 0, 0);
    }
    int e = nt * 16 + lm;
    float bv = u[e];
#pragma unroll
    for (int i = 0; i < 4; ++i) {
      int tl = m0 + lg * 4 + i;
      int byte = tl * 256 + ((e * 2) ^ ((tl & 15) << 4));
      *(unsigned short*)(qs + byte) = f2bf((acc[i] + bv) * QSCALE);
    }
  }
  __syncthreads();
  // coalesced flush: 16KB each, b128
  size_t base = (size_t)(n * TDIM + t0) * 256;
  size_t vbase = (size_t)(n * 128 + (t0 >> 5)) * 8192;
#pragma unroll
  for (int k = 0; k < 4; ++k) {
    int off = tid * 16 + k * 4096;
    *(f32x4*)(Qb + base + off) = *(const f32x4*)(qs + off);
    *(f32x4*)(Kb + base + off) = *(const f32x4*)(kt + off);
    *(f32x4*)(Vt + vbase + off) = *(const f32x4*)(vt + off);
  }
}

// async global -> LDS, 8 KiB per wave
DEVINL void stage8(const char* g, char* s, int ln) {
#pragma unroll
  for (int j = 0; j < 8; ++j) {
    __builtin_amdgcn_global_load_lds(
        (const __attribute__((address_space(1))) void*)(g + j * 1024 + ln * 16),
        (__attribute__((address_space(3))) void*)(s + j * 1024), 16, 0, 0);
  }
}

// counted-drain tile handoff (T4): wave waits only its OWN stage loads
// (issued one full compute-phase ago -> latency hidden), then barrier.
DEVINL void tile_barrier() {
  asm volatile("s_waitcnt vmcnt(0)" ::: "memory");
  __builtin_amdgcn_s_barrier();
  __builtin_amdgcn_sched_barrier(0);
}

// ---------------- kernel 2: flash attention + residual ----------------
// 256 blocks x 512 thr = 2 q-groups (64 q/wave) x 4 kv-streams. KVBLK=32.
// K = raw H (M-trick). Each K/V LDS fragment feeds TWO MFMAs (q-lo/q-hi).
// No-max softmax; in-register P (T12). T4 counted-drain barriers: the stage
// for it+1 is issued at iter top and only waited at iter END (after ~full
// compute phase), instead of __syncthreads' vmcnt(0)-before-barrier drain.
__global__ __launch_bounds__(512, 2) void attn_kernel(
    const char* __restrict__ Qsw, const char* __restrict__ Ksw,
    const char* __restrict__ Vsw, const float* __restrict__ H,
    float* __restrict__ Out) {
  __shared__ __align__(16) char lds[131072];
  int b = blockIdx.x;
  int n = b & 7;  // batch per XCD: H tiles L2-resident
  int q0 = (b >> 3) << 7;
  int tid = threadIdx.x;
  int w = tid >> 6, ln = tid & 63;
  int q32 = ln & 31, hi = ln >> 5;
  int qg = w >> 2;   // q-group (64 q)
  int kvs = w & 3;   // kv stream: [kvs*1024, kvs*1024+1024)
  int qrow = q0 + qg * 64;
  int swz = (q32 & 15) << 4;
  int dpl = q32 >> 1;
  int vcol = (q32 & 1) * 64;

  const char* Kn = Ksw + (size_t)n * (TDIM * 256);
  const char* Vn = Vsw + (size_t)n * (128 * 8192);

  // Q' fragments for both 32-col halves
  const char* Qlo = Qsw + (size_t)(n * TDIM + qrow + q32) * 256;
  const char* Qhi = Qlo + 32 * 256;
  s16x8 qfl[8], qfh[8];
#pragma unroll
  for (int d = 0; d < 8; ++d) {
    int off = (d * 32 + hi * 16) ^ swz;
    qfl[d] = *(const s16x8*)(Qlo + off);
    qfh[d] = *(const s16x8*)(Qhi + off);
  }

  f32x16 o[8];
#pragma unroll
  for (int i = 0; i < 8; ++i) o[i] = (f32x16)0.0f;
  float lsl = 0.f, lsh = 0.f;

  // staging role (independent of compute role): wave stages one 8KB tile
  int stp = w & 3, typ = w >> 2;  // typ 0: K-tile, 1: V-tile
  {
    const char* g = typ ? (Vn + (size_t)(stp * 32) * 8192)
                        : (Kn + (size_t)(stp * 1024) * 256);
    stage8(g, lds + stp * 16384 + typ * 8192, ln);
  }
  tile_barrier();

  for (int it = 0; it < 32; ++it) {
    int c = it & 1;
    if (it < 31) {
      int kvn = stp * 1024 + (it + 1) * 32;
      const char* g = typ ? (Vn + (size_t)(kvn >> 5) * 8192)
                          : (Kn + (size_t)kvn * 256);
      stage8(g, lds + (c ^ 1) * 65536 + stp * 16384 + typ * 8192, ln);
    }
    const char* kb = lds + c * 65536 + kvs * 16384;
    const char* vb = kb + 8192;

    // QK^T swapped: S[kv][q]; A = H rows (32 kv), B = Q' halves
    f32x16 sl = (f32x16)0.0f, sh = (f32x16)0.0f;
    __builtin_amdgcn_s_setprio(1);
#pragma unroll
    for (int d = 0; d < 8; ++d) {
      s16x8 ka = *(const s16x8*)(kb + (q32 * 256 + ((d * 32 + hi * 16) ^ swz)));
      sl = __builtin_amdgcn_mfma_f32_32x32x16_bf16(ka, qfl[d], sl, 0, 0, 0);
      sh = __builtin_amdgcn_mfma_f32_32x32x16_bf16(ka, qfh[d], sh, 0, 0, 0);
    }
    __builtin_amdgcn_s_setprio(0);

    // softmax numerator in place (no max: logits tiny) + row sums
#pragma unroll
    for (int r = 0; r < 16; ++r) {
      sl[r] = __builtin_amdgcn_exp2f(sl[r]);
      lsl += sl[r];
      sh[r] = __builtin_amdgcn_exp2f(sh[r]);
      lsh += sh[r];
    }

    // pack P -> A-fragments in-register (T12), per half
    s16x8 pal[2], pah[2];
    {
      u32 P2[8];
#pragma unroll
      for (int r = 0; r < 8; ++r)
        asm("v_cvt_pk_bf16_f32 %0, %1, %2"
            : "=v"(P2[r]) : "v"(sl[2 * r]), "v"(sl[2 * r + 1]));
#pragma unroll
      for (int b2 = 0; b2 < 2; ++b2) {
        u32 a0 = P2[b2 * 4 + 0], c0 = P2[b2 * 4 + 2];
        u32 a1 = P2[b2 * 4 + 1], c1 = P2[b2 * 4 + 3];
        asm("v_permlane32_swap_b32 %0, %1" : "+v"(a0), "+v"(c0));
        asm("v_permlane32_swap_b32 %0, %1" : "+v"(a1), "+v"(c1));
        union { u32 u[4]; s16x8 v; } pk;
        pk.u[0] = a0; pk.u[1] = a1; pk.u[2] = c0; pk.u[3] = c1;
        pal[b2] = pk.v;
      }
#pragma unroll
      for (int r = 0; r < 8; ++r)
        asm("v_cvt_pk_bf16_f32 %0, %1, %2"
            : "=v"(P2[r]) : "v"(sh[2 * r]), "v"(sh[2 * r + 1]));
#pragma unroll
      for (int b2 = 0; b2 < 2; ++b2) {
        u32 a0 = P2[b2 * 4 + 0], c0 = P2[b2 * 4 + 2];
        u32 a1 = P2[b2 * 4 + 1], c1 = P2[b2 * 4 + 3];
        asm("v_permlane32_swap_b32 %0, %1" : "+v"(a0), "+v"(c0));
        asm("v_permlane32_swap_b32 %0, %1" : "+v"(a1), "+v"(c1));
        union { u32 u[4]; s16x8 v; } pk;
        pk.u[0] = a0; pk.u[1] = a1; pk.u[2] = c0; pk.u[3] = c1;
        pah[b2] = pk.v;
      }
    }

    // PV: each V fragment feeds both q-halves
    __builtin_amdgcn_s_setprio(1);
#pragma unroll
    for (int ks = 0; ks < 2; ++ks) {
#pragma unroll
      for (int dt = 0; dt < 4; ++dt) {
        s16x8 vv = *(const s16x8*)(vb + ((dt * 16 + dpl) * 128 +
                        ((vcol + ks * 32 + hi * 16) ^ ((dpl & 7) << 4))));
        o[dt] = __builtin_amdgcn_mfma_f32_32x32x16_bf16(pal[ks], vv, o[dt], 0, 0, 0);
        o[4 + dt] = __builtin_amdgcn_mfma_f32_32x32x16_bf16(pah[ks], vv, o[4 + dt], 0, 0, 0);
      }
    }
    __builtin_amdgcn_s_setprio(0);
    tile_barrier();  // own stage(it+1) loads done (hidden) + block handoff
  }

  // ---- split-KV merge across 4 streams (tree) ----
  // slots: 4 x 32768 alias the tile region; slot(qg,j) = (qg*2+j)*32768
#define DUMP_O(dst)                                                      \
  {                                                                      \
    char* _d = (dst);                                                    \
    _Pragma("unroll") for (int i = 0; i < 8; ++i)                        \
      _Pragma("unroll") for (int c4 = 0; c4 < 4; ++c4) {                 \
        f32x4 ch = {o[i][c4 * 4 + 0], o[i][c4 * 4 + 1],                  \
                    o[i][c4 * 4 + 2], o[i][c4 * 4 + 3]};                 \
        *(f32x4*)(_d + ((i * 4 + c4) * 64 + ln) * 16) = ch;              \
      }                                                                  \
  }
#define ADD_O(src)                                                       \
  {                                                                      \
    const char* _s = (src);                                              \
    _Pragma("unroll") for (int i = 0; i < 8; ++i)                        \
      _Pragma("unroll") for (int c4 = 0; c4 < 4; ++c4) {                 \
        f32x4 ch = *(const f32x4*)(_s + ((i * 4 + c4) * 64 + ln) * 16);  \
        o[i][c4 * 4 + 0] += ch.x; o[i][c4 * 4 + 1] += ch.y;              \
        o[i][c4 * 4 + 2] += ch.z; o[i][c4 * 4 + 3] += ch.w;              \
      }                                                                  \
  }
  if (kvs & 1) DUMP_O(lds + (qg * 2 + (kvs >> 1)) * 32768);
  __syncthreads();
  if (!(kvs & 1)) ADD_O(lds + (qg * 2 + (kvs >> 1)) * 32768);
  __syncthreads();
  if (kvs == 2) DUMP_O(lds + qg * 2 * 32768);
  // all waves dump l-partials into freed slot qg*2+1
  {
    float* lt = (float*)(lds + (qg * 2 + 1) * 32768);
    lt[((kvs * 2 + hi) * 32 + q32) * 2 + 0] = lsl;
    lt[((kvs * 2 + hi) * 32 + q32) * 2 + 1] = lsh;
  }
  __syncthreads();
  if (kvs == 0) {
    ADD_O(lds + qg * 2 * 32768);
    const float* lt = (const float*)(lds + (qg * 2 + 1) * 32768);
    const float* Hn = H + (size_t)n * TDIM * DDIM;
    float* On = Out + (size_t)n * TDIM * DDIM;
#pragma unroll
    for (int r = 0; r < 16; ++r) {
      int qr = (r & 3) + 8 * (r >> 2) + 4 * hi;
      float suml = 0.f, sumh = 0.f;
#pragma unroll
      for (int t8 = 0; t8 < 8; ++t8) {
        suml += lt[(t8 * 32 + qr) * 2 + 0];
        sumh += lt[(t8 * 32 + qr) * 2 + 1];
      }
      float il = 1.0f / suml, ih = 1.0f / sumh;
#pragma unroll
      for (int dt = 0; dt < 4; ++dt) {
        size_t ilo = (size_t)(qrow + qr) * DDIM + dt * 32 + q32;
        size_t ihi = (size_t)(qrow + 32 + qr) * DDIM + dt * 32 + q32;
        On[ilo] = o[dt][r] * il + Hn[ilo];
        On[ihi] = o[4 + dt][r] * ih + Hn[ihi];
      }
    }
  }
#undef DUMP_O
#undef ADD_O
}

extern "C" void kernel_launch(void* const* d_in, const int* in_sizes, int n_in,
                              void* d_out, int out_size, void* d_ws, size_t ws_size,
                              hipStream_t stream) {
  const float* H  = (const float*)d_in[0];
  const float* Wq = (const float*)d_in[1];
  const float* bq = (const float*)d_in[2];
  const float* Wk = (const float*)d_in[3];
  const float* bk = (const float*)d_in[4];
  (void)bk;  // bk contributes only a row-constant logit term (softmax-invariant)
  float* Out = (float*)d_out;
  char* ws = (char*)d_ws;
  unsigned short* Mt = (unsigned short*)(ws);
  float* u = (float*)(ws + 32768);
  char* Qb = ws + 65536;
  char* Kb = ws + 65536 + 8388608;
  char* Vt = ws + 65536 + 2 * 8388608;

  prep_kernel<<<64, 256, 0, stream>>>(Wq, Wk, bq, Mt, u);
  proj_kernel<<<512, 256, 0, stream>>>(H, Mt, u, Qb, Kb, Vt);
  attn_kernel<<<256, 512, 0, stream>>>(Qb, Kb, Vt, H, Out);
}

// Round 8
// 113.692 us; speedup vs baseline: 1.1094x; 1.0217x over previous
//
#include <hip/hip_runtime.h>
#include <hip/hip_bf16.h>

typedef __attribute__((ext_vector_type(4))) float f32x4;
typedef __attribute__((ext_vector_type(16))) float f32x16;
typedef __attribute__((ext_vector_type(8))) short s16x8;
typedef unsigned int u32;

#define DEVINL static __device__ __forceinline__

constexpr int TDIM = 4096;
constexpr int DDIM = 128;
// softmax logit scale folded into Q' projection: log2(e) / sqrt(T)
constexpr float QSCALE = 1.4426950408889634f / 64.0f;

DEVINL unsigned short f2bf(float f) {
  union { float f; unsigned u; } v; v.f = f;
  unsigned r = v.u + 0x7fffu + ((v.u >> 16) & 1u);
  return (unsigned short)(r >> 16);
}

// ---------------- kernel 0: M = Wq Wk^T (bf16, B-frag layout), u = Wk bq ----
// S[t,s] = (h_t M + u)·h_s + rowconst(t) + const; rowconst cancels in softmax.
__global__ __launch_bounds__(256) void prep_kernel(
    const float* __restrict__ Wq, const float* __restrict__ Wk,
    const float* __restrict__ bq, unsigned short* __restrict__ Mt,
    float* __restrict__ u) {
  int idx = blockIdx.x * 256 + threadIdx.x;  // 16384 entries
  int e = idx >> 7, d = idx & 127;
  float acc = 0.f;
#pragma unroll 4
  for (int h = 0; h < 128; ++h) acc += Wq[d * 128 + h] * Wk[e * 128 + h];
  Mt[e * 128 + d] = f2bf(acc);  // Mt[e][d] = M[d][e]
  if (blockIdx.x == 0 && threadIdx.x < 128) {
    float a = 0.f;
#pragma unroll 4
    for (int h = 0; h < 128; ++h) a += Wk[threadIdx.x * 128 + h] * bq[h];
    u[threadIdx.x] = a;
  }
}

// ---------------- kernel 1: Q' projection + H transcodes ----------------
// Layouts (swizzle baked into global, G21 both-sides):
//   Qb[t][.]: byte = t*256 + ((e*2) ^ ((t&15)<<4))
//   Kb[r][.]: byte = r*256 + ((d*2) ^ ((r&15)<<4))           (bf16 H rows)
//   Vt: per 64-kv tile (16 KB): byte = dp*256 + ((half*128 + tl*2) ^
//       ((dp&15)<<4)),  dp = d>>1, half = d&1, tl = kv&63  (H^T paired rows)
__global__ __launch_bounds__(256) void proj_kernel(
    const float* __restrict__ H, const unsigned short* __restrict__ Mt,
    const float* __restrict__ u, char* __restrict__ Qb,
    char* __restrict__ Kb, char* __restrict__ Vt) {
  __shared__ __align__(16) unsigned short hs[64][136];
  __shared__ __align__(16) char qs[16384];
  __shared__ __align__(16) char kt[16384];
  __shared__ __align__(16) char vt[16384];
  int b = blockIdx.x;
  int n = b >> 6;
  int t0 = (b & 63) << 6;
  int tid = threadIdx.x;
  const float* Hrow = H + (size_t)(n * TDIM + t0) * DDIM;
#pragma unroll
  for (int k = 0; k < 8; ++k) {
    int e = tid + k * 256;
    int r = e >> 5;            // t-local 0..63
    int c = (e & 31) << 2;     // d 0..124
    f32x4 v = *(const f32x4*)(Hrow + r * DDIM + c);
    unsigned short bf[4] = {f2bf(v.x), f2bf(v.y), f2bf(v.z), f2bf(v.w)};
    unsigned short* p = &hs[r][c];
    p[0] = bf[0]; p[1] = bf[1]; p[2] = bf[2]; p[3] = bf[3];
    // Kb tile: 8B block survives the 16B-granule XOR intact
    int kbyte = r * 256 + ((c * 2) ^ ((r & 15) << 4));
    unsigned short* kp = (unsigned short*)(kt + kbyte);
    kp[0] = bf[0]; kp[1] = bf[1]; kp[2] = bf[2]; kp[3] = bf[3];
    // Vt paired-row 16KB tile
#pragma unroll
    for (int j = 0; j < 4; ++j) {
      int d = c + j;
      int dp = d >> 1, half = d & 1;
      int byte = dp * 256 + ((half * 128 + r * 2) ^ ((dp & 15) << 4));
      *(unsigned short*)(vt + byte) = bf[j];
    }
  }
  __syncthreads();
  int w = tid >> 6, ln = tid & 63;
  int lm = ln & 15, lg = ln >> 4;
  int m0 = w * 16;
  s16x8 af[4];
#pragma unroll
  for (int kf = 0; kf < 4; ++kf)
    af[kf] = *(const s16x8*)&hs[m0 + lm][kf * 32 + lg * 8];
  // Q' = H M + u, scaled by QSCALE
#pragma unroll
  for (int nt = 0; nt < 8; ++nt) {
    f32x4 acc = {0.f, 0.f, 0.f, 0.f};
#pragma unroll
    for (int kf = 0; kf < 4; ++kf) {
      s16x8 bfr = *(const s16x8*)&Mt[(nt * 16 + lm) * 128 + kf * 32 + lg * 8];
      acc = __builtin_amdgcn_mfma_f32_16x16x32_bf16(af[kf], bfr, acc, 0, 0, 0);
    }
    int e = nt * 16 + lm;
    float bv = u[e];
#pragma unroll
    for (int i = 0; i < 4; ++i) {
      int tl = m0 + lg * 4 + i;
      int byte = tl * 256 + ((e * 2) ^ ((tl & 15) << 4));
      *(unsigned short*)(qs + byte) = f2bf((acc[i] + bv) * QSCALE);
    }
  }
  __syncthreads();
  // coalesced flush: 16KB each, b128
  size_t base = (size_t)(n * TDIM + t0) * 256;
  size_t vbase = ((size_t)(n * 64 + (t0 >> 6)) << 14);
#pragma unroll
  for (int k = 0; k < 4; ++k) {
    int off = tid * 16 + k * 4096;
    *(f32x4*)(Qb + base + off) = *(const f32x4*)(qs + off);
    *(f32x4*)(Kb + base + off) = *(const f32x4*)(kt + off);
    *(f32x4*)(Vt + vbase + off) = *(const f32x4*)(vt + off);
  }
}

// async global -> LDS, 8 KiB per wave
DEVINL void stage8(const char* g, char* s, int ln) {
#pragma unroll
  for (int j = 0; j < 8; ++j) {
    __builtin_amdgcn_global_load_lds(
        (const __attribute__((address_space(1))) void*)(g + j * 1024 + ln * 16),
        (__attribute__((address_space(3))) void*)(s + j * 1024), 16, 0, 0);
  }
}

// ---------------- kernel 2: flash attention partials ----------------
// 512 blocks x 256 thr (4 waves x 32 q). Block = (batch, kv-stream, q-tile):
// two INDEPENDENT blocks co-reside per CU (64KB LDS each) with uncorrelated
// phases -> QK-MFMA / softmax-VALU / LDS pipes overlap across blocks (m114).
// No-max softmax => split-KV merge is a pure add (o and l), done by a
// separate merge kernel. Stream 0 writes raw o into Out, stream 1 into Op1.
__global__ __launch_bounds__(256, 2) void attn_kernel(
    const char* __restrict__ Qsw, const char* __restrict__ Ksw,
    const char* __restrict__ Vsw, float* __restrict__ Out,
    float* __restrict__ Op1, float* __restrict__ Lp) {
  __shared__ __align__(16) char kbuf[2][16384];
  __shared__ __align__(16) char vbuf[2][16384];
  int b = blockIdx.x;
  int n = b & 7;               // batch per XCD: tiles L2-resident
  int st = (b >> 3) & 1;       // kv stream
  int q0 = (b >> 4) << 7;      // 32 q-tiles of 128
  int tid = threadIdx.x;
  int w = tid >> 6, ln = tid & 63;
  int q32 = ln & 31, hi = ln >> 5;
  int qrow = q0 + w * 32;
  int swz = (q32 & 15) << 4;
  int dpl = q32 >> 1;
  int vswz = dpl << 4;
  int dphalf = (q32 & 1) * 128;

  const char* Kn = Ksw + (size_t)n * (TDIM * 256);
  const char* Vn = Vsw + (size_t)n * (64 * 16384);
  int kv0 = st * 2048;

  // Q' fragments (global rows XOR-swizzled)
  const char* Qn = Qsw + (size_t)(n * TDIM + qrow + q32) * 256;
  s16x8 qf[8];
#pragma unroll
  for (int d = 0; d < 8; ++d)
    qf[d] = *(const s16x8*)(Qn + ((d * 32 + hi * 16) ^ swz));

  f32x16 o[4];
#pragma unroll
  for (int dt = 0; dt < 4; ++dt) o[dt] = (f32x16)0.0f;
  float lsum = 0.f;

  // staging role: wave w stages one 8KB half (w<2: K, w>=2: V)
  {
    const char* g = (w < 2) ? (Kn + (size_t)kv0 * 256 + w * 8192)
                            : (Vn + (size_t)(kv0 >> 6) * 16384 + (w - 2) * 8192);
    char* dst = (w < 2) ? (kbuf[0] + w * 8192) : (vbuf[0] + (w - 2) * 8192);
    stage8(g, dst, ln);
  }
  __syncthreads();

  for (int it = 0; it < 32; ++it) {
    int c = it & 1;
    if (it < 31) {
      int kvn = kv0 + (it + 1) * 64;
      const char* g = (w < 2)
          ? (Kn + (size_t)kvn * 256 + w * 8192)
          : (Vn + (size_t)(kvn >> 6) * 16384 + (w - 2) * 8192);
      char* dst = (w < 2) ? (kbuf[c ^ 1] + w * 8192)
                          : (vbuf[c ^ 1] + (w - 2) * 8192);
      stage8(g, dst, ln);
    }
    const char* kb = kbuf[c];
    const char* vb = vbuf[c];

    // QK^T swapped: S[kv][q], A = H rows (64 kv as two 32-tiles), B = Q'
    f32x16 s0 = (f32x16)0.0f, s1 = (f32x16)0.0f;
    __builtin_amdgcn_s_setprio(1);
#pragma unroll
    for (int d = 0; d < 8; ++d) {
      int col = d * 32 + hi * 16;
      s16x8 ka0 = *(const s16x8*)(kb + ((q32 * 256 + col) ^ swz));
      s16x8 ka1 = *(const s16x8*)(kb + (((q32 + 32) * 256 + col) ^ swz));
      s0 = __builtin_amdgcn_mfma_f32_32x32x16_bf16(ka0, qf[d], s0, 0, 0, 0);
      s1 = __builtin_amdgcn_mfma_f32_32x32x16_bf16(ka1, qf[d], s1, 0, 0, 0);
    }
    __builtin_amdgcn_s_setprio(0);

    // softmax numerator: plain exp2 (no max: |logit| bounded tiny)
    f32x16 p0, p1;
#pragma unroll
    for (int r = 0; r < 16; ++r) {
      p0[r] = __builtin_amdgcn_exp2f(s0[r]);
      p1[r] = __builtin_amdgcn_exp2f(s1[r]);
    }
    float ls = 0.f;
#pragma unroll
    for (int r = 0; r < 16; ++r) ls += p0[r] + p1[r];
    lsum += ls;

    // P -> PV A-fragments fully in-register (T12)
    s16x8 pa[4];
#pragma unroll
    for (int kt2 = 0; kt2 < 2; ++kt2) {
      u32 P2[8];
#pragma unroll
      for (int r = 0; r < 8; ++r) {
        float e0 = kt2 ? p1[2 * r] : p0[2 * r];
        float e1 = kt2 ? p1[2 * r + 1] : p0[2 * r + 1];
        asm("v_cvt_pk_bf16_f32 %0, %1, %2" : "=v"(P2[r]) : "v"(e0), "v"(e1));
      }
#pragma unroll
      for (int b2 = 0; b2 < 2; ++b2) {
        u32 a0 = P2[b2 * 4 + 0], c0 = P2[b2 * 4 + 2];
        u32 a1 = P2[b2 * 4 + 1], c1 = P2[b2 * 4 + 3];
        asm("v_permlane32_swap_b32 %0, %1" : "+v"(a0), "+v"(c0));
        asm("v_permlane32_swap_b32 %0, %1" : "+v"(a1), "+v"(c1));
        union { u32 u[4]; s16x8 v; } pk;
        pk.u[0] = a0; pk.u[1] = a1; pk.u[2] = c0; pk.u[3] = c1;
        pa[kt2 * 2 + b2] = pk.v;
      }
    }

    // PV: o[dt] += P * V, B-frag from paired-row V^T LDS
    __builtin_amdgcn_s_setprio(1);
#pragma unroll
    for (int ks = 0; ks < 4; ++ks) {
      int colv = dphalf + ks * 32 + hi * 16;
#pragma unroll
      for (int dt = 0; dt < 4; ++dt) {
        int dp = dt * 16 + dpl;
        s16x8 vv = *(const s16x8*)(vb + ((dp * 256 + colv) ^ vswz));
        o[dt] = __builtin_amdgcn_mfma_f32_32x32x16_bf16(pa[ks], vv, o[dt], 0, 0, 0);
      }
    }
    __builtin_amdgcn_s_setprio(0);
    __syncthreads();  // 4-wave handoff
  }

  // epilogue: raw partial o (NOT divided) + l partials
  float* Og = st ? Op1 : Out;
#pragma unroll
  for (int r = 0; r < 16; ++r) {
    int qr = (r & 3) + 8 * (r >> 2) + 4 * hi;
    size_t rowbase = (size_t)(n * TDIM + qrow + qr) * DDIM;
#pragma unroll
    for (int dt = 0; dt < 4; ++dt)
      Og[rowbase + dt * 32 + q32] = o[dt][r];
  }
  Lp[(size_t)(n * TDIM + qrow + q32) * 4 + st * 2 + hi] = lsum;
}

// ---------------- kernel 3: merge partials + residual ----------------
// out = (O0 + O1) / (l00+l01+l10+l11) + H.  1024 blocks x 256 thr,
// 32 rows/block, 16 f32 per thread (4 x f32x4).
__global__ __launch_bounds__(256) void merge_kernel(
    float* __restrict__ Out, const float* __restrict__ Op1,
    const float* __restrict__ Lp, const float* __restrict__ H) {
  int tid = threadIdx.x;
  int row = blockIdx.x * 32 + (tid >> 3);
  int col = (tid & 7) * 16;
  f32x4 lp = *(const f32x4*)(Lp + (size_t)row * 4);
  float il = 1.0f / (lp.x + lp.y + lp.z + lp.w);
  size_t base = (size_t)row * DDIM + col;
#pragma unroll
  for (int j = 0; j < 4; ++j) {
    f32x4 a = *(const f32x4*)(Out + base + j * 4);
    f32x4 b2 = *(const f32x4*)(Op1 + base + j * 4);
    f32x4 h = *(const f32x4*)(H + base + j * 4);
    f32x4 r;
    r.x = (a.x + b2.x) * il + h.x;
    r.y = (a.y + b2.y) * il + h.y;
    r.z = (a.z + b2.z) * il + h.z;
    r.w = (a.w + b2.w) * il + h.w;
    *(f32x4*)(Out + base + j * 4) = r;
  }
}

extern "C" void kernel_launch(void* const* d_in, const int* in_sizes, int n_in,
                              void* d_out, int out_size, void* d_ws, size_t ws_size,
                              hipStream_t stream) {
  const float* H  = (const float*)d_in[0];
  const float* Wq = (const float*)d_in[1];
  const float* bq = (const float*)d_in[2];
  const float* Wk = (const float*)d_in[3];
  const float* bk = (const float*)d_in[4];
  (void)bk;  // bk adds only a row-constant logit term (softmax-invariant)
  float* Out = (float*)d_out;
  char* ws = (char*)d_ws;
  unsigned short* Mt = (unsigned short*)(ws);
  float* u = (float*)(ws + 32768);
  char* Qb = ws + 65536;
  char* Kb = Qb + 8388608;
  char* Vt = Kb + 8388608;
  float* Op1 = (float*)(Vt + 8388608);
  float* Lp = (float*)((char*)Op1 + 16777216);

  prep_kernel<<<64, 256, 0, stream>>>(Wq, Wk, bq, Mt, u);
  proj_kernel<<<512, 256, 0, stream>>>(H, Mt, u, Qb, Kb, Vt);
  attn_kernel<<<512, 256, 0, stream>>>(Qb, Kb, Vt, Out, Op1, Lp);
  merge_kernel<<<1024, 256, 0, stream>>>(Out, Op1, Lp, H);
}